// Round 2
// baseline (308.167 us; speedup 1.0000x reference)
//
#include <hip/hip_runtime.h>
#include <hip/hip_bf16.h>
#include <math.h>

// Problem constants
#define INDIM 768
#define NROWS 32768       // 8*4096
#define KSEL  38
#define NCOLS 76          // 2*KSEL
#define CPAD  96          // padded K for MFMA
#define HID   256
#define NPADJ 80
#define LN_EPS 1e-5f

typedef float  f32x4  __attribute__((ext_vector_type(4)));
typedef __bf16 bf16x8 __attribute__((ext_vector_type(8)));

#define MFMA16(a,b,c) __builtin_amdgcn_mfma_f32_16x16x32_bf16((a),(b),(c),0,0,0)

// ---------------- workspace layout (bytes) ----------------
// Bft [96][768] bf16 : analysis basis (rows 76..95 zero)
// Bst [768][96] bf16 : synthesis basis * 2/768 (cols 76..95 zero)
// W1b [2][256][96] bf16 ; W2t [2][80][256] bf16
#define OFF_BFT 0
#define OFF_BST 147456
#define OFF_W1B 294912
#define OFF_W2T 393216

__global__ void k_prep(const int* __restrict__ idxs,
                       const float* __restrict__ mu_w1, const float* __restrict__ sg_w1,
                       const float* __restrict__ mu_w2, const float* __restrict__ sg_w2,
                       __bf16* __restrict__ Bft, __bf16* __restrict__ Bst,
                       __bf16* __restrict__ W1b, __bf16* __restrict__ W2t)
{
    int tid = blockIdx.x * blockDim.x + threadIdx.x;
    int nth = gridDim.x * blockDim.x;
    const float TH = 6.28318530717958647692f / (float)INDIM;

    for (int i = tid; i < CPAD * INDIM; i += nth) {
        int c = i / INDIM, n = i % INDIM;
        float v = 0.f;
        if (c < NCOLS) {
            int cc = (c < KSEL) ? c : c - KSEL;
            int f = idxs[cc];
            int m = (f * n) % INDIM;
            float s, co; sincosf(TH * (float)m, &s, &co);
            v = (c < KSEL) ? co : -s;
        }
        Bft[i] = (__bf16)v;
    }
    for (int i = tid; i < INDIM * CPAD; i += nth) {
        int n = i / CPAD, c = i % CPAD;
        float v = 0.f;
        if (c < NCOLS) {
            int cc = (c < KSEL) ? c : c - KSEL;
            int f = idxs[cc];
            int m = (f * n) % INDIM;
            float s, co; sincosf(TH * (float)m, &s, &co);
            v = ((c < KSEL) ? co : -s) * (2.0f / (float)INDIM);
        }
        Bst[i] = (__bf16)v;
    }
    for (int i = tid; i < 2 * HID * CPAD; i += nth) {
        int mlp = i / (HID * CPAD); int rem = i % (HID * CPAD);
        int r = rem / CPAD, k = rem % CPAD;
        const float* W = mlp ? sg_w1 : mu_w1;
        W1b[i] = (__bf16)((k < NCOLS) ? W[r * NCOLS + k] : 0.f);
    }
    for (int i = tid; i < 2 * NPADJ * HID; i += nth) {
        int mlp = i / (NPADJ * HID); int rem = i % (NPADJ * HID);
        int j = rem / HID, h = rem % HID;
        const float* W = mlp ? sg_w2 : mu_w2;
        W2t[i] = (__bf16)((j < NCOLS) ? W[j * HID + h] : 0.f);
    }
}

static __device__ inline float gelu_exact(float v) {
    return v * 0.5f * (1.f + erff(v * 0.70710678118654752440f));
}

// One wave owns 16 rows end-to-end: DFT -> MLPx2 -> z -> synthesis.
// All LDS is wave-private (no __syncthreads anywhere).
// Per-wave LDS buffer: 4224 bf16, used sequentially as:
//   (1) DFT D-tile transpose, stride 104  (16 x 96)
//   (2) gelu activations,     stride 264  (16 x 256)
//   (3) z transpose,          stride 104  (16 x 96)
__global__ __launch_bounds__(256, 2) void k_fused(
    const float* __restrict__ x, const float* __restrict__ eps,
    const __bf16* __restrict__ Bft, const __bf16* __restrict__ Bst,
    const __bf16* __restrict__ W1b, const __bf16* __restrict__ W2t,
    const float* __restrict__ mu_b1, const float* __restrict__ mu_g,
    const float* __restrict__ mu_be, const float* __restrict__ mu_b2,
    const float* __restrict__ sg_b1, const float* __restrict__ sg_g,
    const float* __restrict__ sg_be, const float* __restrict__ sg_b2,
    float* __restrict__ out)
{
    __shared__ __bf16 sbuf[4 * 4224];
    int tid = threadIdx.x;
    int w = tid >> 6, lane = tid & 63, q = lane >> 4, l16 = lane & 15;
    int rbase = blockIdx.x * 64 + w * 16;
    __bf16* buf = &sbuf[w * 4224];

    // ---------------- Phase 1: DFT (16 rows x 96 cols), K=768 ----------------
    f32x4 acc[6] = {};
    {
        const float* xrow = x + (size_t)(rbase + l16) * INDIM + q * 8;
        float4 f0 = ((const float4*)xrow)[0];
        float4 f1 = ((const float4*)xrow)[1];
        for (int kc = 0; kc < 24; ++kc) {
            int kn = (kc + 1 < 24) ? kc + 1 : kc;
            float4 g0 = ((const float4*)(xrow + kn * 32))[0];
            float4 g1 = ((const float4*)(xrow + kn * 32))[1];
            union { __bf16 h[8]; bf16x8 v; } a;
            a.h[0]=(__bf16)f0.x; a.h[1]=(__bf16)f0.y; a.h[2]=(__bf16)f0.z; a.h[3]=(__bf16)f0.w;
            a.h[4]=(__bf16)f1.x; a.h[5]=(__bf16)f1.y; a.h[6]=(__bf16)f1.z; a.h[7]=(__bf16)f1.w;
            int kb = kc * 32 + q * 8;
            #pragma unroll
            for (int nt = 0; nt < 6; ++nt) {
                bf16x8 b = *(const bf16x8*)&Bft[(size_t)(nt * 16 + l16) * INDIM + kb];
                acc[nt] = MFMA16(a.v, b, acc[nt]);
            }
            f0 = g0; f1 = g1;
        }
    }
    // D-layout [row=q*4+r][col=l16+16nt] -> buf (stride 104) -> A-frags
    #pragma unroll
    for (int nt = 0; nt < 6; ++nt)
        #pragma unroll
        for (int r = 0; r < 4; ++r)
            buf[(q * 4 + r) * 104 + nt * 16 + l16] = (__bf16)acc[nt][r];
    bf16x8 a1[3];
    #pragma unroll
    for (int ks = 0; ks < 3; ++ks)
        a1[ks] = *(const bf16x8*)&buf[l16 * 104 + ks * 32 + q * 8];

    // ---------------- Phase 2: layer1, both MLPs interleaved ----------------
    f32x4 h0[16] = {}, h1[16] = {};
    #pragma unroll
    for (int nt = 0; nt < 16; ++nt) {
        #pragma unroll
        for (int ks = 0; ks < 3; ++ks) {
            bf16x8 b0 = *(const bf16x8*)&W1b[(size_t)(nt * 16 + l16) * CPAD + ks * 32 + q * 8];
            bf16x8 b1 = *(const bf16x8*)&W1b[(size_t)(HID + nt * 16 + l16) * CPAD + ks * 32 + q * 8];
            h0[nt] = MFMA16(a1[ks], b0, h0[nt]);
            h1[nt] = MFMA16(a1[ks], b1, h1[nt]);
        }
    }
    // bias + LN stats for both
    float s0[4] = {}, ss0[4] = {}, s1[4] = {}, ss1[4] = {};
    #pragma unroll
    for (int nt = 0; nt < 16; ++nt) {
        int i = nt * 16 + l16;
        float bb0 = mu_b1[i], bb1 = sg_b1[i];
        #pragma unroll
        for (int r = 0; r < 4; ++r) {
            float v0 = h0[nt][r] + bb0; h0[nt][r] = v0; s0[r] += v0; ss0[r] += v0 * v0;
            float v1 = h1[nt][r] + bb1; h1[nt][r] = v1; s1[r] += v1; ss1[r] += v1 * v1;
        }
    }
    #pragma unroll
    for (int off = 1; off < 16; off <<= 1)
        #pragma unroll
        for (int r = 0; r < 4; ++r) {
            s0[r] += __shfl_xor(s0[r], off);  ss0[r] += __shfl_xor(ss0[r], off);
            s1[r] += __shfl_xor(s1[r], off);  ss1[r] += __shfl_xor(ss1[r], off);
        }
    float mean0[4], rstd0[4], mean1[4], rstd1[4];
    #pragma unroll
    for (int r = 0; r < 4; ++r) {
        mean0[r] = s0[r] * (1.f / 256.f);
        rstd0[r] = rsqrtf(ss0[r] * (1.f / 256.f) - mean0[r] * mean0[r] + LN_EPS);
        mean1[r] = s1[r] * (1.f / 256.f);
        rstd1[r] = rsqrtf(ss1[r] * (1.f / 256.f) - mean1[r] * mean1[r] + LN_EPS);
    }
    // LN + gelu -> buf (stride 264) -> A-frags, mlp0 then mlp1 (buf reused)
    bf16x8 a2[2][8];
    #pragma unroll
    for (int nt = 0; nt < 16; ++nt) {
        int i = nt * 16 + l16;
        float gv = mu_g[i], bev = mu_be[i];
        #pragma unroll
        for (int r = 0; r < 4; ++r)
            buf[(q * 4 + r) * 264 + i] =
                (__bf16)gelu_exact((h0[nt][r] - mean0[r]) * rstd0[r] * gv + bev);
    }
    #pragma unroll
    for (int ks = 0; ks < 8; ++ks)
        a2[0][ks] = *(const bf16x8*)&buf[l16 * 264 + ks * 32 + q * 8];
    #pragma unroll
    for (int nt = 0; nt < 16; ++nt) {
        int i = nt * 16 + l16;
        float gv = sg_g[i], bev = sg_be[i];
        #pragma unroll
        for (int r = 0; r < 4; ++r)
            buf[(q * 4 + r) * 264 + i] =
                (__bf16)gelu_exact((h1[nt][r] - mean1[r]) * rstd1[r] * gv + bev);
    }
    #pragma unroll
    for (int ks = 0; ks < 8; ++ks)
        a2[1][ks] = *(const bf16x8*)&buf[l16 * 264 + ks * 32 + q * 8];

    // ---------------- Phase 3: layer2, both MLPs interleaved ----------------
    f32x4 o[2][5] = {};
    #pragma unroll
    for (int nt = 0; nt < 5; ++nt) {
        #pragma unroll
        for (int ks = 0; ks < 8; ++ks) {
            bf16x8 b0 = *(const bf16x8*)&W2t[(size_t)(nt * 16 + l16) * HID + ks * 32 + q * 8];
            bf16x8 b1 = *(const bf16x8*)&W2t[(size_t)(NPADJ + nt * 16 + l16) * HID + ks * 32 + q * 8];
            o[0][nt] = MFMA16(a2[0][ks], b0, o[0][nt]);
            o[1][nt] = MFMA16(a2[1][ks], b1, o[1][nt]);
        }
    }

    // ---------------- Phase 4: z = mu + eps*sg -> buf (stride 104) ----------------
    #pragma unroll
    for (int nt = 0; nt < 5; ++nt) {
        int j = nt * 16 + l16;
        float b2m = (j < NCOLS) ? mu_b2[j] : 0.f;
        float b2s = (j < NCOLS) ? sg_b2[j] : 0.f;
        #pragma unroll
        for (int r = 0; r < 4; ++r) {
            float z = 0.f;
            if (j < NCOLS) {
                float e = eps[(size_t)(rbase + q * 4 + r) * NCOLS + j];
                z = (o[0][nt][r] + b2m) + e * (o[1][nt][r] + b2s);
            }
            buf[(q * 4 + r) * 104 + j] = (__bf16)z;
        }
    }
    #pragma unroll
    for (int r = 0; r < 4; ++r)
        buf[(q * 4 + r) * 104 + 80 + l16] = (__bf16)0.f;

    bf16x8 az[3];
    #pragma unroll
    for (int ks = 0; ks < 3; ++ks)
        az[ks] = *(const bf16x8*)&buf[l16 * 104 + ks * 32 + q * 8];

    // ---------------- Phase 5: synthesis (16 rows x 768), write out ----------------
    #pragma unroll 8
    for (int nt = 0; nt < 48; ++nt) {
        f32x4 oc = {};
        #pragma unroll
        for (int ks = 0; ks < 3; ++ks) {
            bf16x8 b = *(const bf16x8*)&Bst[(size_t)(nt * 16 + l16) * CPAD + ks * 32 + q * 8];
            oc = MFMA16(az[ks], b, oc);
        }
        #pragma unroll
        for (int r = 0; r < 4; ++r)
            out[(size_t)(rbase + q * 4 + r) * INDIM + nt * 16 + l16] = oc[r];
    }
}

extern "C" void kernel_launch(void* const* d_in, const int* in_sizes, int n_in,
                              void* d_out, int out_size, void* d_ws, size_t ws_size,
                              hipStream_t stream)
{
    const float* x     = (const float*)d_in[0];
    const float* eps   = (const float*)d_in[1];
    const int*   idxs  = (const int*)  d_in[2];
    const float* mu_w1 = (const float*)d_in[3];
    const float* mu_b1 = (const float*)d_in[4];
    const float* mu_g  = (const float*)d_in[5];
    const float* mu_be = (const float*)d_in[6];
    const float* mu_w2 = (const float*)d_in[7];
    const float* mu_b2 = (const float*)d_in[8];
    const float* sg_w1 = (const float*)d_in[9];
    const float* sg_b1 = (const float*)d_in[10];
    const float* sg_g  = (const float*)d_in[11];
    const float* sg_be = (const float*)d_in[12];
    const float* sg_w2 = (const float*)d_in[13];
    const float* sg_b2 = (const float*)d_in[14];
    float* out = (float*)d_out;

    char* ws = (char*)d_ws;
    __bf16* Bft = (__bf16*)(ws + OFF_BFT);
    __bf16* Bst = (__bf16*)(ws + OFF_BST);
    __bf16* W1b = (__bf16*)(ws + OFF_W1B);
    __bf16* W2t = (__bf16*)(ws + OFF_W2T);

    hipLaunchKernelGGL(k_prep, dim3(256), dim3(256), 0, stream,
                       idxs, mu_w1, sg_w1, mu_w2, sg_w2, Bft, Bst, W1b, W2t);
    hipLaunchKernelGGL(k_fused, dim3(NROWS / 64), dim3(256), 0, stream,
                       x, eps, Bft, Bst, W1b, W2t,
                       mu_b1, mu_g, mu_be, mu_b2,
                       sg_b1, sg_g, sg_be, sg_b2, out);
}